// Round 3
// baseline (303.215 us; speedup 1.0000x reference)
//
#include <hip/hip_runtime.h>

// x: (8, 64, 256, 256) fp32; alpha: (1,64,1,1) fp32
// out = x + alpha[c] * sum_{3x3 zero-padded} |x - neighbor|  (center tap = 0)
//
// One wave (64 lanes x float4) = one full 256-wide row.
// Each wave owns a 16-row strip, processed as four pipelined 4-row tiles:
// while computing tile k, the 4 fresh rows of tile k+1 are in flight
// (2 window rows carried in registers -> 18 loads per 16 output rows).
// This keeps ~4KB outstanding per wave for ~the whole wave lifetime --
// fixing the round-2 failure where loads were in flight only ~3% of the
// time (burst->drain->compute) and the memory system sat at 1MB in-flight
// (needs ~8MB for 6.3TB/s at ~900cy latency).
// Fully unrolled, constant indices only (registers, no scratch).
// Block = 4 waves = 64-row slab. Grid = 512 images * 4 slabs = 2048 blocks.

constexpr int H = 256;
constexpr int W = 256;
constexpr int C = 64;

__global__ __launch_bounds__(256) void adc_kernel(
    const float* __restrict__ x,
    const float* __restrict__ alpha,
    float* __restrict__ out)
{
    const int lane = threadIdx.x & 63;
    const int wave = threadIdx.x >> 6;            // 0..3
    const int blk  = blockIdx.x;                  // 0..2047
    const int img  = blk >> 2;                    // 0..511 (b*C + c)
    const int sb   = blk & 3;                     // 64-row slab
    const int y0   = sb * 64 + wave * 16;         // strip start row
    const int c    = img & (C - 1);

    const float  a    = alpha[c];
    const float* imgp = x   + (long)img * (H * W);
    float*       outp = out + (long)img * (H * W);
    const int    w0   = lane * 4;
    const float* base = imgp + (long)y0 * W + w0;

    const float4 z4 = make_float4(0.f, 0.f, 0.f, 0.f);

    // rb[r] holds input row (y0 - 1 + r), r = 0..17. Full unroll, constant
    // indices only -> registers. Live range at tile t is rb[4t .. 4t+9].
    float4 rb[18];

    // ---- Prologue: rows y0-1 .. y0+4 (rb[0..5]) ----
    rb[0] = (y0 > 0) ? *(const float4*)(base - W) : z4;
#pragma unroll
    for (int r = 1; r < 6; ++r)
        rb[r] = *(const float4*)(base + (r - 1) * W);
    __builtin_amdgcn_sched_barrier(0);

#pragma unroll
    for (int t = 0; t < 4; ++t) {
        // ---- Issue tile t+1's 4 fresh rows (stay in flight during compute) ----
        if (t < 3) {
#pragma unroll
            for (int r = 0; r < 4; ++r) {
                const int rr = 6 + 4 * t + r;     // rb slot; row y0 + rr - 1
                const int yy = y0 + rr - 1;
                rb[rr] = (yy < H) ? *(const float4*)(base + (rr - 1) * W) : z4;
            }
            __builtin_amdgcn_sched_barrier(0);
        }

        // ---- Compute tile t: output rows y0+4t .. y0+4t+3 ----
        // Window rows rb[4t .. 4t+5]; halo columns via shuffles.
        float hl[6], hr[6];
#pragma unroll
        for (int r = 0; r < 6; ++r) {
            const float4 f   = rb[4 * t + r];
            const float  lft = __shfl_up(f.w, 1);
            const float  rgt = __shfl_down(f.x, 1);
            hl[r] = (lane == 0)  ? 0.f : lft;     // w0==0 edge -> zero pad
            hr[r] = (lane == 63) ? 0.f : rgt;     // w0+4==W edge -> zero pad
        }

#pragma unroll
        for (int o = 0; o < 4; ++o) {
            // 3 window rows for this output row, expanded to 6 wide.
            float e[3][6];
#pragma unroll
            for (int r = 0; r < 3; ++r) {
                const float4 f = rb[4 * t + o + r];
                e[r][0] = hl[o + r];
                e[r][1] = f.x; e[r][2] = f.y; e[r][3] = f.z; e[r][4] = f.w;
                e[r][5] = hr[o + r];
            }
            float4 res;
            float* rp = &res.x;
#pragma unroll
            for (int j = 0; j < 4; ++j) {
                const float xc = e[1][j + 1];
                float s = 0.f;
#pragma unroll
                for (int r = 0; r < 3; ++r)
#pragma unroll
                    for (int d = 0; d < 3; ++d)
                        s += fabsf(xc - e[r][j + d]);   // center tap adds 0
                rp[j] = fmaf(a, s, xc);
            }
            *(float4*)(outp + (long)(y0 + 4 * t + o) * W + w0) = res;
        }
    }
}

extern "C" void kernel_launch(void* const* d_in, const int* in_sizes, int n_in,
                              void* d_out, int out_size, void* d_ws, size_t ws_size,
                              hipStream_t stream)
{
    const float* x     = (const float*)d_in[0];
    const float* alpha = (const float*)d_in[1];
    float*       out   = (float*)d_out;

    const int grid = 8 * C * (H / 64);   // 512 images * 4 slabs = 2048
    adc_kernel<<<grid, 256, 0, stream>>>(x, alpha, out);
}

// Round 5
// 236.564 us; speedup vs baseline: 1.2817x; 1.2817x over previous
//
#include <hip/hip_runtime.h>

// x: (8, 64, 256, 256) fp32; alpha: (1,64,1,1) fp32
// out = x + alpha[c] * sum_{3x3 zero-padded} |x - neighbor|  (center tap = 0)
//
// One wave (64 lanes x float4) = one full 256-wide row.
// Each wave owns a 32-row strip, processed as 8 software-pipelined 4-row
// tiles: while computing tile t, tile t+1's 4 rows are in flight. ALL
// pipeline state is in NAMED float4 scalars (c0..c5 window, n0..n3
// prefetch) rotated in a fully-unrolled loop -> rotation is register
// renaming, no arrays, no scratch. (Round 3's rb[18] array spilled:
// WRITE_SIZE 131->278MB of scratch traffic at VGPR=44.)
// This gives fillBuffer-like streaming (long-lived waves, loads never
// drain to vmcnt 0: compiler's per-use wait is ~vmcnt(8) with stores +
// next prefetch outstanding) -- vs rounds 0-2's burst->drain->die waves
// that each paid a full queued-memory latency per 4 output rows.
// Block = 4 waves; wave w owns rows [half*128 + w*32, +32).
// Grid = 512 images * 2 halves = 1024 blocks = exactly 4 blocks/CU.

constexpr int H = 256;
constexpr int W = 256;
constexpr int C = 64;

__global__ __launch_bounds__(256, 4) void adc_kernel(
    const float* __restrict__ x,
    const float* __restrict__ alpha,
    float* __restrict__ out)
{
    const int lane = threadIdx.x & 63;
    const int wave = threadIdx.x >> 6;            // 0..3
    const int blk  = blockIdx.x;                  // 0..1023
    const int img  = blk >> 1;                    // 0..511 (b*C + c)
    const int half = blk & 1;
    const int y0   = half * 128 + wave * 32;      // strip start row
    const int c    = img & (C - 1);

    const float  a     = alpha[c];
    const float* imgp  = x   + (long)img * (H * W);
    float*       outp  = out + (long)img * (H * W);
    const int    w0    = lane * 4;
    const float* base  = imgp + (long)y0 * W + w0;
    float*       obase = outp + (long)y0 * W + w0;

    const float4 z4 = make_float4(0.f, 0.f, 0.f, 0.f);

    // Window: c0..c5 hold input rows y0+4t-1 .. y0+4t+4 at tile t.
    // Prefetch: n0..n3 hold tile t+1's fresh rows y0+4t+5 .. y0+4t+8.
    float4 c0, c1, c2, c3, c4, c5, n0, n1, n2, n3;

    // ---- Prologue: rows y0-1 .. y0+4 (y0+4 <= 228 < H always) ----
    c0 = (y0 > 0) ? *(const float4*)(base - W) : z4;
    c1 = *(const float4*)(base);
    c2 = *(const float4*)(base + W);
    c3 = *(const float4*)(base + 2 * W);
    c4 = *(const float4*)(base + 3 * W);
    c5 = *(const float4*)(base + 4 * W);
    __builtin_amdgcn_sched_barrier(0);

#pragma unroll
    for (int t = 0; t < 8; ++t) {
        // ---- Issue tile t+1's rows (stay in flight during compute) ----
        if (t < 7) {
            const int r0 = 4 * t + 5;             // rows y0+r0 .. y0+r0+3
            n0 = *(const float4*)(base + r0 * W);          // <= y0+29 < H
            n1 = *(const float4*)(base + (r0 + 1) * W);    // <= y0+30 < H
            n2 = *(const float4*)(base + (r0 + 2) * W);    // <= y0+31 < H
            n3 = (y0 + r0 + 3 < H)                         // y0+32 may == H
                     ? *(const float4*)(base + (r0 + 3) * W) : z4;
            __builtin_amdgcn_sched_barrier(0);
        }

        // ---- Compute tile t from c0..c5 ----
        float e[6][6];
#define EXPAND_ROW(k, f)                                            \
        {                                                           \
            e[k][1] = (f).x; e[k][2] = (f).y;                       \
            e[k][3] = (f).z; e[k][4] = (f).w;                       \
            const float lft = __shfl_up((f).w, 1);                  \
            const float rgt = __shfl_down((f).x, 1);                \
            e[k][0] = (lane == 0)  ? 0.f : lft;  /* w==0 pad */     \
            e[k][5] = (lane == 63) ? 0.f : rgt;  /* w==W pad */     \
        }
        EXPAND_ROW(0, c0)
        EXPAND_ROW(1, c1)
        EXPAND_ROW(2, c2)
        EXPAND_ROW(3, c3)
        EXPAND_ROW(4, c4)
        EXPAND_ROW(5, c5)
#undef EXPAND_ROW

#pragma unroll
        for (int o = 0; o < 4; ++o) {
            float4 res;
            float* rp = &res.x;
#pragma unroll
            for (int j = 0; j < 4; ++j) {
                const float xc = e[o + 1][j + 1];
                float s = 0.f;
#pragma unroll
                for (int r = 0; r < 3; ++r)
#pragma unroll
                    for (int d = 0; d < 3; ++d)
                        s += fabsf(xc - e[o + r][j + d]);  // center adds 0
                rp[j] = fmaf(a, s, xc);
            }
            *(float4*)(obase + (4 * t + o) * W) = res;
        }

        // ---- Rotate window (register renames under full unroll) ----
        c0 = c4; c1 = c5; c2 = n0; c3 = n1; c4 = n2; c5 = n3;
    }
}

extern "C" void kernel_launch(void* const* d_in, const int* in_sizes, int n_in,
                              void* d_out, int out_size, void* d_ws, size_t ws_size,
                              hipStream_t stream)
{
    const float* x     = (const float*)d_in[0];
    const float* alpha = (const float*)d_in[1];
    float*       out   = (float*)d_out;

    const int grid = 8 * C * 2;          // 512 images * 2 halves = 1024
    adc_kernel<<<grid, 256, 0, stream>>>(x, alpha, out);
}

// Round 6
// 230.144 us; speedup vs baseline: 1.3175x; 1.0279x over previous
//
#include <hip/hip_runtime.h>

// x: (8, 64, 256, 256) fp32; alpha: (1,64,1,1) fp32
// out = x + alpha[c] * sum_{3x3 zero-padded} |x - neighbor|  (center tap = 0)
//
// Diagnosis after 5 rounds: hipcc's register allocator sinks plain-C++ loads
// to their first use (VGPR stayed 32-48 across every structure), so at most
// ~1 load/wave is ever in flight -> ~14k-cycle stall per tile, both pipes
// <35% busy, flat 82-87us. Fix: loads are opaque inline-asm
// global_load_dwordx4 ("=v" outputs CANNOT be sunk or live-range-split),
// with hand-counted s_waitcnt vmcnt(N) (never 0 in steady state) +
// sched_barrier(0) (rule: compiler ignores asm hazards).
// Depth-2 pipeline: 3 rotating 4-row register sets; while tile t is
// computed, tiles t+1 and t+2 (8 loads) + 2 store sets are outstanding.
// Counted waits from the exact issue stream: 8,12,16,16,16,16,12,8.
// Wave = full 256-wide row (64 lanes x float4); strip = 32 rows = 8 tiles.
// Grid = 512 images * 2 halves = 1024 blocks * 4 waves.

typedef float f32x4 __attribute__((ext_vector_type(4)));

constexpr int H = 256;
constexpr int W = 256;
constexpr int C = 64;

#define GLOAD(dst, ptr) \
    asm volatile("global_load_dwordx4 %0, %1, off" : "=v"(dst) : "v"(ptr))
#define WAITV_I(n) asm volatile("s_waitcnt vmcnt(" #n ")" ::: "memory")
#define WAITV(n) do { WAITV_I(n); __builtin_amdgcn_sched_barrier(0); } while (0)

#define EXPAND(k, f)                                              \
    {                                                             \
        e[k][1] = (f).x; e[k][2] = (f).y;                         \
        e[k][3] = (f).z; e[k][4] = (f).w;                         \
        const float lft = __shfl_up((f).w, 1);                    \
        const float rgt = __shfl_down((f).x, 1);                  \
        e[k][0] = (lane == 0)  ? 0.f : lft;  /* w==0 pad */       \
        e[k][5] = (lane == 63) ? 0.f : rgt;  /* w==W pad */       \
    }

// Iteration T: optionally issue P(T+2) (rows y0+4T+9 .. +12) into F*_,
// wait until P(T) (= P0_..P3_) is complete, compute output rows
// y0+4T .. y0+4T+3, carry last two window rows into c0,c1.
#define ITER(T, P0_, P1_, P2_, P3_, F0_, F1_, F2_, F3_, ISSUE, WN, FIX)  \
    {                                                                    \
        if (ISSUE) {                                                     \
            const int r0 = 4 * (T) + 9;                                  \
            GLOAD(F0_, base + (r0 + 0) * W);                             \
            GLOAD(F1_, base + (r0 + 1) * W);                             \
            GLOAD(F2_, base + (r0 + 2) * W);                             \
            GLOAD(F3_, base + ((y0 + r0 + 3 < H) ? (r0 + 3) : 0) * W);   \
        }                                                                \
        WAITV(WN);                                                       \
        FIX                                                              \
        float e[6][6];                                                   \
        EXPAND(0, c0) EXPAND(1, c1) EXPAND(2, P0_) EXPAND(3, P1_)        \
        EXPAND(4, P2_) EXPAND(5, P3_)                                    \
        _Pragma("unroll")                                                \
        for (int o = 0; o < 4; ++o) {                                    \
            f32x4 res;                                                   \
            _Pragma("unroll")                                            \
            for (int j = 0; j < 4; ++j) {                                \
                const float xc = e[o + 1][j + 1];                        \
                float s = 0.f;                                           \
                _Pragma("unroll")                                        \
                for (int r = 0; r < 3; ++r)                              \
                    _Pragma("unroll")                                    \
                    for (int d = 0; d < 3; ++d)                          \
                        s += fabsf(xc - e[o + r][j + d]);                \
                res[j] = fmaf(a, s, xc);                                 \
            }                                                            \
            *(f32x4*)(obase + (4 * (T) + o) * W) = res;                  \
        }                                                                \
        c0 = P2_; c1 = P3_;                                              \
    }

__global__ __launch_bounds__(256, 2) void adc_kernel(
    const float* __restrict__ x,
    const float* __restrict__ alpha,
    float* __restrict__ out)
{
    const int lane = threadIdx.x & 63;
    const int wave = threadIdx.x >> 6;            // 0..3
    const int blk  = blockIdx.x;                  // 0..1023
    const int img  = blk >> 1;                    // 0..511 (b*C + c)
    const int half = blk & 1;
    const int y0   = half * 128 + wave * 32;      // strip start row
    const int c    = img & (C - 1);

    const float a = alpha[c];
    // Anchor: the alpha access (if it compiles to a vector load) must retire
    // before the counted-vmcnt pipeline starts, or the counts are wrong.
    WAITV(0);

    const float* imgp  = x   + (long)img * (H * W);
    float*       outp  = out + (long)img * (H * W);
    const int    w0    = lane * 4;
    const float* base  = imgp + (long)y0 * W + w0;
    float*       obase = outp + (long)y0 * W + w0;

    const f32x4 z4f = {0.f, 0.f, 0.f, 0.f};

    // Window carries (rows y0+4t-1, y0+4t) and three rotating 4-row sets:
    // P(t) lives in set (t % 3): A=P0,P3,P6  B=P1,P4,P7  C=P2,P5.
    f32x4 c0, c1;
    f32x4 pA0, pA1, pA2, pA3;
    f32x4 pB0, pB1, pB2, pB3;
    f32x4 pC0, pC1, pC2, pC3;

    // ---- Prologue: c0(row y0-1, clamped), c1(row y0), P0(rows +1..+4),
    //      P1(rows +5..+8). 10 loads in flight. ----
    GLOAD(c0, base + ((y0 > 0) ? -W : 0));
    GLOAD(c1, base);
    GLOAD(pA0, base + 1 * W);
    GLOAD(pA1, base + 2 * W);
    GLOAD(pA2, base + 3 * W);
    GLOAD(pA3, base + 4 * W);
    GLOAD(pB0, base + 5 * W);
    GLOAD(pB1, base + 6 * W);
    GLOAD(pB2, base + 7 * W);
    GLOAD(pB3, base + 8 * W);

    //      tile   P(t) set              issue set (P(t+2))     issue wn
    ITER(0, pA0, pA1, pA2, pA3, pC0, pC1, pC2, pC3, true,  8,
         if (y0 == 0) c0 = z4f;)
    ITER(1, pB0, pB1, pB2, pB3, pA0, pA1, pA2, pA3, true,  12, {})
    ITER(2, pC0, pC1, pC2, pC3, pB0, pB1, pB2, pB3, true,  16, {})
    ITER(3, pA0, pA1, pA2, pA3, pC0, pC1, pC2, pC3, true,  16, {})
    ITER(4, pB0, pB1, pB2, pB3, pA0, pA1, pA2, pA3, true,  16, {})
    ITER(5, pC0, pC1, pC2, pC3, pB0, pB1, pB2, pB3, true,  16, {})
    ITER(6, pA0, pA1, pA2, pA3, pA0, pA1, pA2, pA3, false, 12, {})
    ITER(7, pB0, pB1, pB2, pB3, pB0, pB1, pB2, pB3, false, 8,
         if (y0 + 32 >= H) pB3 = z4f;)
}

extern "C" void kernel_launch(void* const* d_in, const int* in_sizes, int n_in,
                              void* d_out, int out_size, void* d_ws, size_t ws_size,
                              hipStream_t stream)
{
    const float* x     = (const float*)d_in[0];
    const float* alpha = (const float*)d_in[1];
    float*       out   = (float*)d_out;

    const int grid = 8 * C * 2;          // 512 images * 2 halves = 1024
    adc_kernel<<<grid, 256, 0, stream>>>(x, alpha, out);
}

// Round 7
// 228.143 us; speedup vs baseline: 1.3291x; 1.0088x over previous
//
#include <hip/hip_runtime.h>
#include <stdint.h>

// x: (8, 64, 256, 256) fp32; alpha: (1,64,1,1) fp32
// out = x + alpha[c] * sum_{3x3 zero-padded} |x - neighbor|  (center tap = 0)
//
// Round-7 structure: LDS-staged slabs via __builtin_amdgcn_global_load_lds.
// Rationale (R0-R6 evidence): register-return loads cap at ~2.5 TB/s on this
// pattern no matter the source structure (regalloc sinks loads; forcing MLP
// via asm in R6 did NOT raise BW -> per-CU memory-queue is the limit and
// load result-registers are the scarce resource). global_load_lds makes
// reads fire-and-forget like stores (fillBuffer streams 6.5 TB/s at 8 VGPR),
// with zero VGPR cost, issued back-to-back.
// - Block (256t) stages 18 rows (16 + 2 halo) of one image into LDS
//   (1 KB/row/wave-instr), one __syncthreads, computes 16 rows.
// - LDS row = [4 zero dwords][256 data][zero][pad] stride 264 dwords:
//   horizontal halo = direct LDS read (no shuffles/cndmask); 8-bank
//   rotation per row.
// - 19 KB LDS -> 8 blocks/CU -> 32 waves/CU (100% occupancy): barrier
//   drains are masked by 7 co-resident blocks.
// - Non-temporal stores: out (134 MB) won't evict x from the 256 MB L3
//   (x+out > L3; currently half the reads miss to HBM).
// - XCD-aware decode: all 16 slabs of an image on one XCD's L2.

typedef float f32x4 __attribute__((ext_vector_type(4)));

constexpr int H = 256;
constexpr int W = 256;
constexpr int C = 64;
constexpr int SLAB = 16;            // output rows per block
constexpr int NR   = SLAB + 2;      // staged rows incl. vertical halo
constexpr int RSTR = 264;           // LDS row stride in dwords (1056 B)

typedef const uint32_t __attribute__((address_space(1)))* gas_t;
typedef uint32_t __attribute__((address_space(3)))* las_t;

__global__ __launch_bounds__(256) void adc_kernel(
    const float* __restrict__ x,
    const float* __restrict__ alpha,
    float* __restrict__ out)
{
    __shared__ float lds[NR * RSTR];          // 18*264*4 = 19,008 B

    const int tid  = threadIdx.x;
    const int lane = tid & 63;
    const int wave = tid >> 6;                // 0..3

    // XCD-friendly decode: grid 8192 = 8 xcd * 64 img-group * 16 slabs.
    // Default dispatch round-robins blockIdx over 8 XCDs -> images with
    // img%8==xcd stay on one XCD's L2 (image = 256 KB).
    const int n     = blockIdx.x;
    const int xcd   = n & 7;
    const int local = n >> 3;                 // 0..1023
    const int img   = ((local >> 4) << 3) + xcd;   // 0..511, img%8==xcd
    const int slab  = local & 15;
    const int y0    = slab * SLAB;

    const float a = alpha[img & (C - 1)];
    const float* imgp = x   + (long)img * (H * W);
    float*       outp = out + (long)img * (H * W);

    // ---- Zero the halo pad slots (dwords 0..3 and 260 of each row) ----
    if (tid < NR) {
        *(f32x4*)&lds[tid * RSTR] = (f32x4){0.f, 0.f, 0.f, 0.f};
        lds[tid * RSTR + 260] = 0.f;
    }

    // ---- Stage rows y0-1 .. y0+16 (fire-and-forget, no result VGPRs) ----
#pragma unroll
    for (int r = wave; r < NR; r += 4) {
        const int g = y0 + r - 1;
        if (g >= 0 && g < H) {
            const float* gsrc = imgp + (long)g * W + lane * 4;
            // LDS dest: wave-uniform base; HW writes base + lane*16 (m104).
            __builtin_amdgcn_global_load_lds((gas_t)gsrc,
                                             (las_t)&lds[r * RSTR + 4],
                                             16, 0, 0);
        } else {
            // vertical zero-pad row (image top/bottom)
            *(f32x4*)&lds[r * RSTR + 4 + lane * 4] =
                (f32x4){0.f, 0.f, 0.f, 0.f};
        }
    }
    __syncthreads();

    // ---- Compute: wave handles output rows y0+4*wave .. +3 ----
    const int r0    = wave * 4 + 1;           // LDS row of first output row
    const int cbase = 4 + lane * 4;           // dword index of lane's quad

    f32x4 eq[3];                              // rolling 3-row window
    float eL[3], eR[3];
#pragma unroll
    for (int k = 0; k < 2; ++k) {             // rows r0-1, r0
        const int rr = r0 - 1 + k;
        eq[k] = *(const f32x4*)&lds[rr * RSTR + cbase];
        eL[k] = lds[rr * RSTR + cbase - 1];   // lane0 -> pad slot = 0
        eR[k] = lds[rr * RSTR + cbase + 4];   // lane63 -> pad slot = 0
    }

    float* orow0 = outp + (long)(y0 + wave * 4) * W + lane * 4;

#pragma unroll
    for (int o = 0; o < 4; ++o) {
        const int s = (o + 2) % 3, t = o % 3, m = (o + 1) % 3;
        const int rr = r0 + o + 1;            // new bottom window row
        eq[s] = *(const f32x4*)&lds[rr * RSTR + cbase];
        eL[s] = lds[rr * RSTR + cbase - 1];
        eR[s] = lds[rr * RSTR + cbase + 4];

        float e[3][6];
#pragma unroll
        for (int k = 0; k < 3; ++k) {
            const int kk = (k == 0) ? t : ((k == 1) ? m : s);  // const idx
            e[k][0] = eL[kk];
            e[k][1] = eq[kk].x; e[k][2] = eq[kk].y;
            e[k][3] = eq[kk].z; e[k][4] = eq[kk].w;
            e[k][5] = eR[kk];
        }

        f32x4 res;
#pragma unroll
        for (int j = 0; j < 4; ++j) {
            const float xc = e[1][j + 1];
            float sacc = 0.f;
#pragma unroll
            for (int r2 = 0; r2 < 3; ++r2)
#pragma unroll
                for (int d = 0; d < 3; ++d)
                    sacc += fabsf(xc - e[r2][j + d]);   // center adds 0
            res[j] = fmaf(a, sacc, xc);
        }
        __builtin_nontemporal_store(res, (f32x4*)(orow0 + o * W));
    }
}

extern "C" void kernel_launch(void* const* d_in, const int* in_sizes, int n_in,
                              void* d_out, int out_size, void* d_ws, size_t ws_size,
                              hipStream_t stream)
{
    const float* x     = (const float*)d_in[0];
    const float* alpha = (const float*)d_in[1];
    float*       out   = (float*)d_out;

    const int grid = 8 * C * (H / SLAB);   // 512 images * 16 slabs = 8192
    adc_kernel<<<grid, 256, 0, stream>>>(x, alpha, out);
}